// Round 11
// baseline (379.304 us; speedup 1.0000x reference)
//
#include <hip/hip_runtime.h>
#include <float.h>

// PretrainingGIN on MI355X — Round 11.
// R10 post-mortem: k_fused is fabric-bound (217MB @ ~3TB/s = its 73us), at the
// compulsory-replication fetch floor. Remaining fat is the ~151us of "other".
// Changes:
//  - k_bucket standalone; csr|cast|pack merged into one k_mid kernel so the
//    391 latency-bound csr blocks hide under 12.5k streaming cast blocks.
//  - Max-pool fused into layer-2 k_fused epilogue: 2x shfl_xor row-reduction
//    (single-graph waves; per-row atomic fallback at graph boundaries) +
//    encoded-uint atomicMax; k_dec decodes. Removes pool1's 12.8MB re-read.
//  - One memset covers gcnt + pool partial. 7 launches total.

#define N_NODES 100000
#define N_EDGES 1600000
#define DIM 128
#define NGRAPHS 64

#define NBUCK 391          // ceil(100000/256) buckets of 256 nodes
#define BCAP 5120          // max edges/bucket (mean 4096, +16 sigma)
#define CCAP 6144          // ssrc ints per bucket (edges + per-node align pad)
#define EPT 8              // edges per thread in bucket pass
#define EPB 2048           // 256*8 edges per block

#define NB_BUCKET ((N_EDGES + EPB - 1) / EPB)          // 782
#define NB_CAST   (N_NODES * DIM / 4 / 256)            // 12500
#define NB_PACK   (6 * DIM * DIM / 256)                // 384

#define BROWS 32           // rows per fused block (16 per wave, 2 waves)
#define LSTRIDE 136        // bf16 elems; 272B rows keep 16B align
#define IDXCAP 512         // staged indices per wave (sum deg ~280, 14-sigma)

typedef __attribute__((ext_vector_type(8))) short bf16x8;
typedef __attribute__((ext_vector_type(4))) float f32x4;

__device__ inline float bflo(unsigned u) { return __uint_as_float(u << 16); }
__device__ inline float bfhi(unsigned u) { return __uint_as_float(u & 0xffff0000u); }

__device__ inline unsigned short f2bf(float a) {      // RNE
    unsigned u = __float_as_uint(a);
    u = u + 0x7fff + ((u >> 16) & 1);
    return (unsigned short)(u >> 16);
}
__device__ inline unsigned f2bf_pack(float a, float b) {
    unsigned ua = __float_as_uint(a), ub = __float_as_uint(b);
    ua = ua + 0x7fff + ((ua >> 16) & 1);
    ub = ub + 0x7fff + ((ub >> 16) & 1);
    return (ua >> 16) | (ub & 0xffff0000u);
}

// monotonic float<->uint encoding for atomicMax over signed floats
__device__ inline unsigned encf(float f) {
    int b = __float_as_int(f);
    return (b >= 0) ? ((unsigned)b | 0x80000000u) : ~(unsigned)b;
}

// ---------------- bucket the edges (standalone; csr depends on it) ----------------
__global__ __launch_bounds__(256) void k_bucket(const int* __restrict__ src,
                                                const int* __restrict__ dst,
                                                int* __restrict__ gcnt,
                                                unsigned* __restrict__ store) {
    __shared__ int hist[NBUCK];
    __shared__ int base[NBUCK];
    const int t = threadIdx.x;
    const int e0 = blockIdx.x * EPB;

    for (int i = t; i < NBUCK; i += 256) hist[i] = 0;
    __syncthreads();

    int bk[EPT], rk[EPT];
    unsigned pk[EPT];
#pragma unroll
    for (int k = 0; k < EPT; ++k) {
        int e = e0 + k * 256 + t;
        bk[k] = -1;
        if (e < N_EDGES) {
            int d = dst[e];
            int s = src[e];
            int bb = d >> 8;
            bk[k] = bb;
            rk[k] = atomicAdd(&hist[bb], 1);
            pk[k] = ((unsigned)(d & 255) << 17) | (unsigned)s;
        }
    }
    __syncthreads();
    for (int i = t; i < NBUCK; i += 256)
        if (hist[i] > 0) base[i] = atomicAdd(&gcnt[i], hist[i]);
    __syncthreads();
#pragma unroll
    for (int k = 0; k < EPT; ++k) {
        if (bk[k] >= 0) {
            int p = base[bk[k]] + rk[k];
            if (p < BCAP) store[(size_t)bk[k] * BCAP + p] = pk[k];
        }
    }
}

// ---------------- mid kernel: csr | cast | pack ----------------
// Blocks [0,NBUCK): per-bucket CSR fill (latency-bound, few blocks) hidden
// under blocks [NBUCK, NBUCK+NB_CAST): x->bf16 streaming cast; tail: W pack.
__global__ __launch_bounds__(256) void k_mid(const unsigned* __restrict__ store,
                                             const int* __restrict__ gcnt,
                                             int* __restrict__ offs,
                                             int* __restrict__ deg,
                                             int* __restrict__ ssrc,
                                             const float* __restrict__ x,
                                             unsigned short* __restrict__ hA,
                                             const float* __restrict__ W1,
                                             const float* __restrict__ W2,
                                             unsigned short* __restrict__ pack) {
    __shared__ int hist[256];
    __shared__ int s[256];
    __shared__ int pos[256];
    const int b = blockIdx.x;
    const int t = threadIdx.x;

    if (b < NBUCK) {
        // ---- per-bucket CSR fill ----
        int nE = gcnt[b];
        if (nE > BCAP) nE = BCAP;

        hist[t] = 0;
        __syncthreads();
        const unsigned* bs = store + (size_t)b * BCAP;
        for (int e = t; e < nE; e += 256)
            atomicAdd(&hist[bs[e] >> 17], 1);
        __syncthreads();

        int cnt = hist[t];
        int al = (cnt + 3) & ~3;          // 16B-align each node's segment
        s[t] = al;
        __syncthreads();
        for (int off = 1; off < 256; off <<= 1) {
            int xv = (t >= off) ? s[t - off] : 0;
            __syncthreads();
            s[t] += xv;
            __syncthreads();
        }
        int loc = s[t] - al;              // exclusive prefix
        int node = b * 256 + t;
        if (node < N_NODES) {
            offs[node] = b * CCAP + loc;
            deg[node] = cnt;
        }
        pos[t] = loc;
        __syncthreads();

        int* outp = ssrc + (size_t)b * CCAP;
        for (int e = t; e < nE; e += 256) {
            unsigned p = bs[e];
            int dl = p >> 17;
            int q = atomicAdd(&pos[dl], 1);
            outp[q] = (int)(p & 0x1FFFFu);
        }
    } else if (b < NBUCK + NB_CAST) {
        // ---- cast x -> bf16 ----
        int i = ((b - NBUCK) * 256 + t) * 4;
        float4 v = *(const float4*)(x + i);
        uint2 o;
        o.x = f2bf_pack(v.x, v.y);
        o.y = f2bf_pack(v.z, v.w);
        *(uint2*)(hA + i) = o;
    } else {
        // ---- repack W into B-fragment order bf16 ----
        int tid = (b - NBUCK - NB_CAST) * 256 + t;
        int mat = tid >> 14;
        int e = tid & 16383;
        int k = e >> 7, c = e & 127;
        const float* W = (mat < 3) ? (W1 + mat * DIM * DIM)
                                   : (W2 + (mat - 3) * DIM * DIM);
        int kb = k >> 5, q = (k >> 3) & 3, j = k & 7;
        pack[mat * DIM * DIM + kb * 4096 + c * 32 + q * 8 + j] = f2bf(W[k * DIM + c]);
    }
}

// ---------------- fused layer: h_out = MLP(h + sum_{j->i} h_j) [+ pool] ----------------
__global__ __launch_bounds__(128) void k_fused(const unsigned short* __restrict__ h,
                                               const int* __restrict__ offs,
                                               const int* __restrict__ deg,
                                               const int* __restrict__ ssrc,
                                               unsigned short* __restrict__ hout,
                                               const unsigned short* __restrict__ Wp1,
                                               const float* __restrict__ b1,
                                               const unsigned short* __restrict__ Wp2,
                                               const float* __restrict__ b2,
                                               int relu_out,
                                               const int* __restrict__ batch,
                                               unsigned* __restrict__ poolp) {
    __shared__ int idx[2][IDXCAP];                    // 4096 B
    __shared__ unsigned short buf[BROWS * LSTRIDE];   // 8704 B
    const int tid = threadIdx.x;
    const int wv = tid >> 6, lane = tid & 63;
    const int q = lane >> 4, n = lane & 15;
    const int sub = lane >> 4, ln16 = lane & 15;
    const int row0 = blockIdx.x * BROWS;
    const int nb0 = row0 + wv * 16;                   // wave's first node

    // ---- stage the wave's indices (contiguous CSR range) into LDS ----
    const int base0 = offs[nb0];
    int cnt = offs[nb0 + 15] + deg[nb0 + 15] - base0;
    if (cnt > IDXCAP) cnt = IDXCAP;
    for (int i = lane * 4; i < cnt; i += 256) {
        int4 v = *(const int4*)(ssrc + base0 + i);
        *(int4*)&idx[wv][i] = v;
    }

    // ---- gather: 4 iterations x 4 parallel rows; per-node loop bounds ----
#pragma unroll 1
    for (int j = 0; j < 4; ++j) {
        const int node = nb0 + j * 4 + sub;
        const unsigned short* hb = h + (size_t)node * DIM + ln16 * 8;
        uint4 sv = *(const uint4*)hb;
        float a0 = bflo(sv.x), a1 = bfhi(sv.x);
        float a2 = bflo(sv.y), a3 = bfhi(sv.y);
        float a4 = bflo(sv.z), a5 = bfhi(sv.z);
        float a6 = bflo(sv.w), a7 = bfhi(sv.w);

        int loc = offs[node] - base0;                 // 4-aligned
        const int dgv = deg[node];
        const int bound4 = (dgv + 3) & ~3;            // node's own segment
        if (loc > IDXCAP - 8) loc = IDXCAP - 8;       // safety

#define ACC(RK, K)                                                        \
            {                                                             \
                unsigned w0 = (e + (K) < dgv) ? RK.x : 0u;                \
                unsigned w1 = (e + (K) < dgv) ? RK.y : 0u;                \
                unsigned w2 = (e + (K) < dgv) ? RK.z : 0u;                \
                unsigned w3 = (e + (K) < dgv) ? RK.w : 0u;                \
                a0 += bflo(w0); a1 += bfhi(w0);                           \
                a2 += bflo(w1); a3 += bfhi(w1);                           \
                a4 += bflo(w2); a5 += bfhi(w2);                           \
                a6 += bflo(w3); a7 += bfhi(w3);                           \
            }

        int e = 0;
        for (; e + 8 <= bound4; e += 8) {
            int4 iA = *(const int4*)&idx[wv][loc + e];
            int4 iB = *(const int4*)&idx[wv][loc + e + 4];
            int s0 = min(iA.x & 0x1FFFF, N_NODES - 1);
            int s1 = min(iA.y & 0x1FFFF, N_NODES - 1);
            int s2 = min(iA.z & 0x1FFFF, N_NODES - 1);
            int s3 = min(iA.w & 0x1FFFF, N_NODES - 1);
            int s4 = min(iB.x & 0x1FFFF, N_NODES - 1);
            int s5 = min(iB.y & 0x1FFFF, N_NODES - 1);
            int s6 = min(iB.z & 0x1FFFF, N_NODES - 1);
            int s7 = min(iB.w & 0x1FFFF, N_NODES - 1);
            uint4 r0 = *(const uint4*)(h + (size_t)s0 * DIM + ln16 * 8);
            uint4 r1 = *(const uint4*)(h + (size_t)s1 * DIM + ln16 * 8);
            uint4 r2 = *(const uint4*)(h + (size_t)s2 * DIM + ln16 * 8);
            uint4 r3 = *(const uint4*)(h + (size_t)s3 * DIM + ln16 * 8);
            uint4 r4 = *(const uint4*)(h + (size_t)s4 * DIM + ln16 * 8);
            uint4 r5 = *(const uint4*)(h + (size_t)s5 * DIM + ln16 * 8);
            uint4 r6 = *(const uint4*)(h + (size_t)s6 * DIM + ln16 * 8);
            uint4 r7 = *(const uint4*)(h + (size_t)s7 * DIM + ln16 * 8);
            ACC(r0, 0) ACC(r1, 1) ACC(r2, 2) ACC(r3, 3)
            ACC(r4, 4) ACC(r5, 5) ACC(r6, 6) ACC(r7, 7)
        }
        if (e < bound4) {
            int4 iA = *(const int4*)&idx[wv][loc + e];
            int s0 = min(iA.x & 0x1FFFF, N_NODES - 1);
            int s1 = min(iA.y & 0x1FFFF, N_NODES - 1);
            int s2 = min(iA.z & 0x1FFFF, N_NODES - 1);
            int s3 = min(iA.w & 0x1FFFF, N_NODES - 1);
            uint4 r0 = *(const uint4*)(h + (size_t)s0 * DIM + ln16 * 8);
            uint4 r1 = *(const uint4*)(h + (size_t)s1 * DIM + ln16 * 8);
            uint4 r2 = *(const uint4*)(h + (size_t)s2 * DIM + ln16 * 8);
            uint4 r3 = *(const uint4*)(h + (size_t)s3 * DIM + ln16 * 8);
            ACC(r0, 0) ACC(r1, 1) ACC(r2, 2) ACC(r3, 3)
        }
#undef ACC

        uint4 o;
        o.x = f2bf_pack(a0, a1);
        o.y = f2bf_pack(a2, a3);
        o.z = f2bf_pack(a4, a5);
        o.w = f2bf_pack(a6, a7);
        *(uint4*)&buf[(wv * 16 + j * 4 + sub) * LSTRIDE + ln16 * 8] = o;
    }

    // ---- A1 fragments ----
    bf16x8 a1f[4];
    {
        const unsigned short* mr = buf + (wv * 16 + n) * LSTRIDE + q * 8;
#pragma unroll
        for (int kb = 0; kb < 4; ++kb) a1f[kb] = *(const bf16x8*)(mr + kb * 32);
    }

    float bia1[8], bia2[8];
#pragma unroll
    for (int ct = 0; ct < 8; ++ct) {
        bia1[ct] = b1[ct * 16 + n];
        bia2[ct] = b2[ct * 16 + n];
    }

    // ---- GEMM1 ----
#pragma unroll
    for (int ct = 0; ct < 8; ++ct) {
        f32x4 acc = {0.f, 0.f, 0.f, 0.f};
#pragma unroll
        for (int kb = 0; kb < 4; ++kb) {
            bf16x8 b = *(const bf16x8*)(Wp1 + kb * 4096 + (ct * 16 + n) * 32 + q * 8);
            acc = __builtin_amdgcn_mfma_f32_16x16x32_bf16(a1f[kb], b, acc, 0, 0, 0);
        }
#pragma unroll
        for (int r = 0; r < 4; ++r)
            buf[(wv * 16 + q * 4 + r) * LSTRIDE + ct * 16 + n] =
                f2bf(fmaxf(acc[r] + bia1[ct], 0.f));
    }

    // ---- A2 fragments ----
    bf16x8 a2f[4];
    {
        const unsigned short* tr = buf + (wv * 16 + n) * LSTRIDE + q * 8;
#pragma unroll
        for (int kb = 0; kb < 4; ++kb) a2f[kb] = *(const bf16x8*)(tr + kb * 32);
    }

    // ---- pool setup (layer 2 only; wave-uniform branch) ----
    const bool dopool = (poolp != nullptr);
    int bg0 = 0, bguni = 0, bgr[4];
    if (dopool) {
#pragma unroll
        for (int r = 0; r < 4; ++r) bgr[r] = batch[nb0 + q * 4 + r];
        bg0 = batch[nb0];
        bguni = (bg0 == batch[nb0 + 15]);
    }

    // ---- GEMM2 (+ fused max-pool epilogue) ----
#pragma unroll
    for (int ct = 0; ct < 8; ++ct) {
        f32x4 acc = {0.f, 0.f, 0.f, 0.f};
#pragma unroll
        for (int kb = 0; kb < 4; ++kb) {
            bf16x8 b = *(const bf16x8*)(Wp2 + kb * 4096 + (ct * 16 + n) * 32 + q * 8);
            acc = __builtin_amdgcn_mfma_f32_16x16x32_bf16(a2f[kb], b, acc, 0, 0, 0);
        }
        float vmax = -FLT_MAX;
#pragma unroll
        for (int r = 0; r < 4; ++r) {
            float v = acc[r] + bia2[ct];
            if (relu_out) v = fmaxf(v, 0.f);
            buf[(wv * 16 + q * 4 + r) * LSTRIDE + ct * 16 + n] = f2bf(v);
            if (dopool) {
                if (bguni) vmax = fmaxf(vmax, v);
                else atomicMax(&poolp[bgr[r] * DIM + ct * 16 + n], encf(v));
            }
        }
        if (dopool && bguni) {
            vmax = fmaxf(vmax, __shfl_xor(vmax, 16));
            vmax = fmaxf(vmax, __shfl_xor(vmax, 32));
            if (q == 0) atomicMax(&poolp[bg0 * DIM + ct * 16 + n], encf(vmax));
        }
    }

    // ---- store own wave's 16 rows ----
    {
#pragma unroll
        for (int s2 = 0; s2 < 4; ++s2) {
            int lr = wv * 16 + s2 * 4 + (lane >> 4);
            int c0 = (lane & 15) * 8;
            *(bf16x8*)(hout + (size_t)(row0 + lr) * DIM + c0) =
                *(const bf16x8*)(buf + lr * LSTRIDE + c0);
        }
    }
}

// ---------------- decode pool partial -> out ----------------
__global__ __launch_bounds__(256) void k_dec(const unsigned* __restrict__ poolp,
                                             float* __restrict__ out) {
    int i = blockIdx.x * 256 + threadIdx.x;   // 8192 total
    unsigned u = poolp[i];
    int b = (u & 0x80000000u) ? (int)(u & 0x7FFFFFFFu) : (int)~u;
    out[i] = __int_as_float(b);
}

extern "C" void kernel_launch(void* const* d_in, const int* in_sizes, int n_in,
                              void* d_out, int out_size, void* d_ws, size_t ws_size,
                              hipStream_t stream) {
    const float* x   = (const float*)d_in[0];
    const int* ei    = (const int*)d_in[1];
    const int* batch = (const int*)d_in[2];
    const float* W1  = (const float*)d_in[3];
    const float* b1  = (const float*)d_in[4];
    const float* W2  = (const float*)d_in[5];
    const float* b2  = (const float*)d_in[6];
    float* out = (float*)d_out;

    const int* src = ei;
    const int* dst = ei + N_EDGES;

    unsigned short* hA  = (unsigned short*)d_ws;                   // 25.6 MB
    unsigned short* hB  = hA + (size_t)N_NODES * DIM;              // 25.6 MB
    unsigned* store     = (unsigned*)(hB + (size_t)N_NODES * DIM); // 8.0 MB
    int* ssrc           = (int*)(store + (size_t)NBUCK * BCAP);    // 9.6 MB
    int* offs           = ssrc + (size_t)NBUCK * CCAP + 64;        // 400 KB
    int* deg            = offs + N_NODES;                          // 400 KB
    int* gcnt           = deg + N_NODES;                           // NBUCK
    unsigned* poolp     = (unsigned*)(gcnt + NBUCK + 1);           // 32 KB
    unsigned short* wpk = (unsigned short*)(poolp + NGRAPHS * DIM);// 192 KB

    // one memset covers gcnt + pool partial (0 = -inf under encoding)
    hipMemsetAsync(gcnt, 0, (NBUCK + 1 + NGRAPHS * DIM) * sizeof(int), stream);
    k_bucket<<<NB_BUCKET, 256, 0, stream>>>(src, dst, gcnt, store);
    k_mid<<<NBUCK + NB_CAST + NB_PACK, 256, 0, stream>>>(
        store, gcnt, offs, deg, ssrc, x, hA, W1, W2, wpk);

    const int fusedBlocks = N_NODES / BROWS;   // 3125 exactly
    unsigned short* Wp1 = wpk;
    unsigned short* Wp2 = wpk + 3 * DIM * DIM;

    // 3 fused layers, ping-pong hA <-> hB; layer 2 pools inline
    k_fused<<<fusedBlocks, 128, 0, stream>>>(hA, offs, deg, ssrc, hB,
                                             Wp1, b1, Wp2, b2, 1,
                                             batch, nullptr);
    k_fused<<<fusedBlocks, 128, 0, stream>>>(hB, offs, deg, ssrc, hA,
                                             Wp1 + DIM * DIM, b1 + DIM,
                                             Wp2 + DIM * DIM, b2 + DIM, 1,
                                             batch, nullptr);
    k_fused<<<fusedBlocks, 128, 0, stream>>>(hA, offs, deg, ssrc, hB,
                                             Wp1 + 2 * DIM * DIM, b1 + 2 * DIM,
                                             Wp2 + 2 * DIM * DIM, b2 + 2 * DIM, 0,
                                             batch, poolp);

    // decode pooled maxima
    k_dec<<<NGRAPHS * DIM / 256, 256, 0, stream>>>(poolp, out);
}

// Round 12
// 372.040 us; speedup vs baseline: 1.0195x; 1.0195x over previous
//
#include <hip/hip_runtime.h>
#include <float.h>

// PretrainingGIN on MI355X — Round 12.
// R11 post-mortem: pool-fused epilogue spilled registers (VGPR 48->64, +3.8MB
// scratch WRITE on ALL layers, 73->86us). Revert to lean k_fused (R10) +
// two-stage pool; KEEP the k_mid merge (csr hidden under cast), which saved
// ~29us of "other".

#define N_NODES 100000
#define N_EDGES 1600000
#define DIM 128
#define NGRAPHS 64
#define PCHUNK 16          // pool stage-1 chunks per graph

#define NBUCK 391          // ceil(100000/256) buckets of 256 nodes
#define BCAP 5120          // max edges/bucket (mean 4096, +16 sigma)
#define CCAP 6144          // ssrc ints per bucket (edges + per-node align pad)
#define EPT 8              // edges per thread in bucket pass
#define EPB 2048           // 256*8 edges per block

#define NB_BUCKET ((N_EDGES + EPB - 1) / EPB)          // 782
#define NB_CAST   (N_NODES * DIM / 4 / 256)            // 12500
#define NB_PACK   (6 * DIM * DIM / 256)                // 384

#define BROWS 32           // rows per fused block (16 per wave, 2 waves)
#define LSTRIDE 136        // bf16 elems; 272B rows keep 16B align
#define IDXCAP 512         // staged indices per wave (sum deg ~280, 14-sigma)

typedef __attribute__((ext_vector_type(8))) short bf16x8;
typedef __attribute__((ext_vector_type(4))) float f32x4;

__device__ inline float bflo(unsigned u) { return __uint_as_float(u << 16); }
__device__ inline float bfhi(unsigned u) { return __uint_as_float(u & 0xffff0000u); }

__device__ inline unsigned short f2bf(float a) {      // RNE
    unsigned u = __float_as_uint(a);
    u = u + 0x7fff + ((u >> 16) & 1);
    return (unsigned short)(u >> 16);
}
__device__ inline unsigned f2bf_pack(float a, float b) {
    unsigned ua = __float_as_uint(a), ub = __float_as_uint(b);
    ua = ua + 0x7fff + ((ua >> 16) & 1);
    ub = ub + 0x7fff + ((ub >> 16) & 1);
    return (ua >> 16) | (ub & 0xffff0000u);
}

// ---------------- bucket the edges (standalone; csr depends on it) ----------------
__global__ __launch_bounds__(256) void k_bucket(const int* __restrict__ src,
                                                const int* __restrict__ dst,
                                                int* __restrict__ gcnt,
                                                unsigned* __restrict__ store) {
    __shared__ int hist[NBUCK];
    __shared__ int base[NBUCK];
    const int t = threadIdx.x;
    const int e0 = blockIdx.x * EPB;

    for (int i = t; i < NBUCK; i += 256) hist[i] = 0;
    __syncthreads();

    int bk[EPT], rk[EPT];
    unsigned pk[EPT];
#pragma unroll
    for (int k = 0; k < EPT; ++k) {
        int e = e0 + k * 256 + t;
        bk[k] = -1;
        if (e < N_EDGES) {
            int d = dst[e];
            int s = src[e];
            int bb = d >> 8;
            bk[k] = bb;
            rk[k] = atomicAdd(&hist[bb], 1);
            pk[k] = ((unsigned)(d & 255) << 17) | (unsigned)s;
        }
    }
    __syncthreads();
    for (int i = t; i < NBUCK; i += 256)
        if (hist[i] > 0) base[i] = atomicAdd(&gcnt[i], hist[i]);
    __syncthreads();
#pragma unroll
    for (int k = 0; k < EPT; ++k) {
        if (bk[k] >= 0) {
            int p = base[bk[k]] + rk[k];
            if (p < BCAP) store[(size_t)bk[k] * BCAP + p] = pk[k];
        }
    }
}

// ---------------- mid kernel: csr | cast | pack ----------------
__global__ __launch_bounds__(256) void k_mid(const unsigned* __restrict__ store,
                                             const int* __restrict__ gcnt,
                                             int* __restrict__ offs,
                                             int* __restrict__ deg,
                                             int* __restrict__ ssrc,
                                             const float* __restrict__ x,
                                             unsigned short* __restrict__ hA,
                                             const float* __restrict__ W1,
                                             const float* __restrict__ W2,
                                             unsigned short* __restrict__ pack) {
    __shared__ int hist[256];
    __shared__ int s[256];
    __shared__ int pos[256];
    const int b = blockIdx.x;
    const int t = threadIdx.x;

    if (b < NBUCK) {
        // ---- per-bucket CSR fill ----
        int nE = gcnt[b];
        if (nE > BCAP) nE = BCAP;

        hist[t] = 0;
        __syncthreads();
        const unsigned* bs = store + (size_t)b * BCAP;
        for (int e = t; e < nE; e += 256)
            atomicAdd(&hist[bs[e] >> 17], 1);
        __syncthreads();

        int cnt = hist[t];
        int al = (cnt + 3) & ~3;          // 16B-align each node's segment
        s[t] = al;
        __syncthreads();
        for (int off = 1; off < 256; off <<= 1) {
            int xv = (t >= off) ? s[t - off] : 0;
            __syncthreads();
            s[t] += xv;
            __syncthreads();
        }
        int loc = s[t] - al;              // exclusive prefix
        int node = b * 256 + t;
        if (node < N_NODES) {
            offs[node] = b * CCAP + loc;
            deg[node] = cnt;
        }
        pos[t] = loc;
        __syncthreads();

        int* outp = ssrc + (size_t)b * CCAP;
        for (int e = t; e < nE; e += 256) {
            unsigned p = bs[e];
            int dl = p >> 17;
            int q = atomicAdd(&pos[dl], 1);
            outp[q] = (int)(p & 0x1FFFFu);
        }
    } else if (b < NBUCK + NB_CAST) {
        // ---- cast x -> bf16 ----
        int i = ((b - NBUCK) * 256 + t) * 4;
        float4 v = *(const float4*)(x + i);
        uint2 o;
        o.x = f2bf_pack(v.x, v.y);
        o.y = f2bf_pack(v.z, v.w);
        *(uint2*)(hA + i) = o;
    } else {
        // ---- repack W into B-fragment order bf16 ----
        int tid = (b - NBUCK - NB_CAST) * 256 + t;
        int mat = tid >> 14;
        int e = tid & 16383;
        int k = e >> 7, c = e & 127;
        const float* W = (mat < 3) ? (W1 + mat * DIM * DIM)
                                   : (W2 + (mat - 3) * DIM * DIM);
        int kb = k >> 5, q = (k >> 3) & 3, j = k & 7;
        pack[mat * DIM * DIM + kb * 4096 + c * 32 + q * 8 + j] = f2bf(W[k * DIM + c]);
    }
}

// ---------------- fused layer: h_out = MLP(h + sum_{j->i} h_j) ----------------
__global__ __launch_bounds__(128) void k_fused(const unsigned short* __restrict__ h,
                                               const int* __restrict__ offs,
                                               const int* __restrict__ deg,
                                               const int* __restrict__ ssrc,
                                               unsigned short* __restrict__ hout,
                                               const unsigned short* __restrict__ Wp1,
                                               const float* __restrict__ b1,
                                               const unsigned short* __restrict__ Wp2,
                                               const float* __restrict__ b2,
                                               int relu_out) {
    __shared__ int idx[2][IDXCAP];                    // 4096 B
    __shared__ unsigned short buf[BROWS * LSTRIDE];   // 8704 B
    const int tid = threadIdx.x;
    const int wv = tid >> 6, lane = tid & 63;
    const int q = lane >> 4, n = lane & 15;
    const int sub = lane >> 4, ln16 = lane & 15;
    const int row0 = blockIdx.x * BROWS;
    const int nb0 = row0 + wv * 16;                   // wave's first node

    // ---- stage the wave's indices (contiguous CSR range) into LDS ----
    const int base0 = offs[nb0];
    int cnt = offs[nb0 + 15] + deg[nb0 + 15] - base0;
    if (cnt > IDXCAP) cnt = IDXCAP;
    for (int i = lane * 4; i < cnt; i += 256) {
        int4 v = *(const int4*)(ssrc + base0 + i);
        *(int4*)&idx[wv][i] = v;
    }

    // ---- gather: 4 iterations x 4 parallel rows; per-node loop bounds ----
#pragma unroll 1
    for (int j = 0; j < 4; ++j) {
        const int node = nb0 + j * 4 + sub;
        const unsigned short* hb = h + (size_t)node * DIM + ln16 * 8;
        uint4 sv = *(const uint4*)hb;
        float a0 = bflo(sv.x), a1 = bfhi(sv.x);
        float a2 = bflo(sv.y), a3 = bfhi(sv.y);
        float a4 = bflo(sv.z), a5 = bfhi(sv.z);
        float a6 = bflo(sv.w), a7 = bfhi(sv.w);

        int loc = offs[node] - base0;                 // 4-aligned
        const int dgv = deg[node];
        const int bound4 = (dgv + 3) & ~3;            // node's own segment
        if (loc > IDXCAP - 8) loc = IDXCAP - 8;       // safety

#define ACC(RK, K)                                                        \
            {                                                             \
                unsigned w0 = (e + (K) < dgv) ? RK.x : 0u;                \
                unsigned w1 = (e + (K) < dgv) ? RK.y : 0u;                \
                unsigned w2 = (e + (K) < dgv) ? RK.z : 0u;                \
                unsigned w3 = (e + (K) < dgv) ? RK.w : 0u;                \
                a0 += bflo(w0); a1 += bfhi(w0);                           \
                a2 += bflo(w1); a3 += bfhi(w1);                           \
                a4 += bflo(w2); a5 += bfhi(w2);                           \
                a6 += bflo(w3); a7 += bfhi(w3);                           \
            }

        int e = 0;
        for (; e + 8 <= bound4; e += 8) {
            int4 iA = *(const int4*)&idx[wv][loc + e];
            int4 iB = *(const int4*)&idx[wv][loc + e + 4];
            int s0 = min(iA.x & 0x1FFFF, N_NODES - 1);
            int s1 = min(iA.y & 0x1FFFF, N_NODES - 1);
            int s2 = min(iA.z & 0x1FFFF, N_NODES - 1);
            int s3 = min(iA.w & 0x1FFFF, N_NODES - 1);
            int s4 = min(iB.x & 0x1FFFF, N_NODES - 1);
            int s5 = min(iB.y & 0x1FFFF, N_NODES - 1);
            int s6 = min(iB.z & 0x1FFFF, N_NODES - 1);
            int s7 = min(iB.w & 0x1FFFF, N_NODES - 1);
            uint4 r0 = *(const uint4*)(h + (size_t)s0 * DIM + ln16 * 8);
            uint4 r1 = *(const uint4*)(h + (size_t)s1 * DIM + ln16 * 8);
            uint4 r2 = *(const uint4*)(h + (size_t)s2 * DIM + ln16 * 8);
            uint4 r3 = *(const uint4*)(h + (size_t)s3 * DIM + ln16 * 8);
            uint4 r4 = *(const uint4*)(h + (size_t)s4 * DIM + ln16 * 8);
            uint4 r5 = *(const uint4*)(h + (size_t)s5 * DIM + ln16 * 8);
            uint4 r6 = *(const uint4*)(h + (size_t)s6 * DIM + ln16 * 8);
            uint4 r7 = *(const uint4*)(h + (size_t)s7 * DIM + ln16 * 8);
            ACC(r0, 0) ACC(r1, 1) ACC(r2, 2) ACC(r3, 3)
            ACC(r4, 4) ACC(r5, 5) ACC(r6, 6) ACC(r7, 7)
        }
        if (e < bound4) {
            int4 iA = *(const int4*)&idx[wv][loc + e];
            int s0 = min(iA.x & 0x1FFFF, N_NODES - 1);
            int s1 = min(iA.y & 0x1FFFF, N_NODES - 1);
            int s2 = min(iA.z & 0x1FFFF, N_NODES - 1);
            int s3 = min(iA.w & 0x1FFFF, N_NODES - 1);
            uint4 r0 = *(const uint4*)(h + (size_t)s0 * DIM + ln16 * 8);
            uint4 r1 = *(const uint4*)(h + (size_t)s1 * DIM + ln16 * 8);
            uint4 r2 = *(const uint4*)(h + (size_t)s2 * DIM + ln16 * 8);
            uint4 r3 = *(const uint4*)(h + (size_t)s3 * DIM + ln16 * 8);
            ACC(r0, 0) ACC(r1, 1) ACC(r2, 2) ACC(r3, 3)
        }
#undef ACC

        uint4 o;
        o.x = f2bf_pack(a0, a1);
        o.y = f2bf_pack(a2, a3);
        o.z = f2bf_pack(a4, a5);
        o.w = f2bf_pack(a6, a7);
        *(uint4*)&buf[(wv * 16 + j * 4 + sub) * LSTRIDE + ln16 * 8] = o;
    }

    // ---- A1 fragments ----
    bf16x8 a1f[4];
    {
        const unsigned short* mr = buf + (wv * 16 + n) * LSTRIDE + q * 8;
#pragma unroll
        for (int kb = 0; kb < 4; ++kb) a1f[kb] = *(const bf16x8*)(mr + kb * 32);
    }

    float bia1[8], bia2[8];
#pragma unroll
    for (int ct = 0; ct < 8; ++ct) {
        bia1[ct] = b1[ct * 16 + n];
        bia2[ct] = b2[ct * 16 + n];
    }

    // ---- GEMM1 ----
#pragma unroll
    for (int ct = 0; ct < 8; ++ct) {
        f32x4 acc = {0.f, 0.f, 0.f, 0.f};
#pragma unroll
        for (int kb = 0; kb < 4; ++kb) {
            bf16x8 b = *(const bf16x8*)(Wp1 + kb * 4096 + (ct * 16 + n) * 32 + q * 8);
            acc = __builtin_amdgcn_mfma_f32_16x16x32_bf16(a1f[kb], b, acc, 0, 0, 0);
        }
#pragma unroll
        for (int r = 0; r < 4; ++r)
            buf[(wv * 16 + q * 4 + r) * LSTRIDE + ct * 16 + n] =
                f2bf(fmaxf(acc[r] + bia1[ct], 0.f));
    }

    // ---- A2 fragments ----
    bf16x8 a2f[4];
    {
        const unsigned short* tr = buf + (wv * 16 + n) * LSTRIDE + q * 8;
#pragma unroll
        for (int kb = 0; kb < 4; ++kb) a2f[kb] = *(const bf16x8*)(tr + kb * 32);
    }

    // ---- GEMM2 ----
#pragma unroll
    for (int ct = 0; ct < 8; ++ct) {
        f32x4 acc = {0.f, 0.f, 0.f, 0.f};
#pragma unroll
        for (int kb = 0; kb < 4; ++kb) {
            bf16x8 b = *(const bf16x8*)(Wp2 + kb * 4096 + (ct * 16 + n) * 32 + q * 8);
            acc = __builtin_amdgcn_mfma_f32_16x16x32_bf16(a2f[kb], b, acc, 0, 0, 0);
        }
#pragma unroll
        for (int r = 0; r < 4; ++r) {
            float v = acc[r] + bia2[ct];
            if (relu_out) v = fmaxf(v, 0.f);
            buf[(wv * 16 + q * 4 + r) * LSTRIDE + ct * 16 + n] = f2bf(v);
        }
    }

    // ---- store own wave's 16 rows ----
    {
#pragma unroll
        for (int s2 = 0; s2 < 4; ++s2) {
            int lr = wv * 16 + s2 * 4 + (lane >> 4);
            int c0 = (lane & 15) * 8;
            *(bf16x8*)(hout + (size_t)(row0 + lr) * DIM + c0) =
                *(const bf16x8*)(buf + lr * LSTRIDE + c0);
        }
    }
}

// ---------------- pool (two-stage; starts inline in stage 1) ----------------
__device__ inline int lbound(const int* __restrict__ batch, int g) {
    int lo = 0, hi = N_NODES;
    while (lo < hi) {
        int mid = (lo + hi) >> 1;
        if (batch[mid] < g) lo = mid + 1;
        else hi = mid;
    }
    return lo;
}

__global__ __launch_bounds__(256) void k_pool1(const unsigned short* __restrict__ h,
                                               const int* __restrict__ batch,
                                               float* __restrict__ partial) {
    __shared__ float red[4][DIM];
    __shared__ int sb[2];
    int g = blockIdx.x, c = blockIdx.y;
    int t = threadIdx.x;
    if (t < 2) sb[t] = lbound(batch, g + t);
    __syncthreads();
    int i0 = sb[0], i1 = sb[1];
    int rowpar = t >> 6;
    int col = (t & 63) * 2;
    float mx = -FLT_MAX, my = -FLT_MAX;
    for (int i = i0 + c * 4 + rowpar; i < i1; i += 64) {
        unsigned u = *(const unsigned*)(h + (size_t)i * DIM + col);
        mx = fmaxf(mx, bflo(u));
        my = fmaxf(my, bfhi(u));
    }
    red[rowpar][col] = mx;
    red[rowpar][col + 1] = my;
    __syncthreads();
    if (rowpar == 0) {
        mx = fmaxf(fmaxf(red[0][col], red[1][col]), fmaxf(red[2][col], red[3][col]));
        my = fmaxf(fmaxf(red[0][col + 1], red[1][col + 1]),
                   fmaxf(red[2][col + 1], red[3][col + 1]));
        float* p = partial + ((size_t)g * PCHUNK + c) * DIM;
        p[col] = mx;
        p[col + 1] = my;
    }
}

__global__ __launch_bounds__(128) void k_pool2(const float* __restrict__ partial,
                                               float* __restrict__ out) {
    int g = blockIdx.x;
    int col = threadIdx.x;
    const float* p = partial + (size_t)g * PCHUNK * DIM + col;
    float m = p[0];
#pragma unroll
    for (int c = 1; c < PCHUNK; ++c) m = fmaxf(m, p[c * DIM]);
    out[g * DIM + col] = m;
}

extern "C" void kernel_launch(void* const* d_in, const int* in_sizes, int n_in,
                              void* d_out, int out_size, void* d_ws, size_t ws_size,
                              hipStream_t stream) {
    const float* x   = (const float*)d_in[0];
    const int* ei    = (const int*)d_in[1];
    const int* batch = (const int*)d_in[2];
    const float* W1  = (const float*)d_in[3];
    const float* b1  = (const float*)d_in[4];
    const float* W2  = (const float*)d_in[5];
    const float* b2  = (const float*)d_in[6];
    float* out = (float*)d_out;

    const int* src = ei;
    const int* dst = ei + N_EDGES;

    unsigned short* hA  = (unsigned short*)d_ws;                   // 25.6 MB
    unsigned short* hB  = hA + (size_t)N_NODES * DIM;              // 25.6 MB
    unsigned* store     = (unsigned*)(hB + (size_t)N_NODES * DIM); // 8.0 MB
    int* ssrc           = (int*)(store + (size_t)NBUCK * BCAP);    // 9.6 MB
    int* offs           = ssrc + (size_t)NBUCK * CCAP + 64;        // 400 KB
    int* deg            = offs + N_NODES;                          // 400 KB
    int* gcnt           = deg + N_NODES;                           // NBUCK
    unsigned short* wpk = (unsigned short*)(gcnt + NBUCK + 1);     // 192 KB
    float* partial      = (float*)(wpk + 6 * DIM * DIM);           // 512 KB

    hipMemsetAsync(gcnt, 0, NBUCK * sizeof(int), stream);
    k_bucket<<<NB_BUCKET, 256, 0, stream>>>(src, dst, gcnt, store);
    k_mid<<<NBUCK + NB_CAST + NB_PACK, 256, 0, stream>>>(
        store, gcnt, offs, deg, ssrc, x, hA, W1, W2, wpk);

    const int fusedBlocks = N_NODES / BROWS;   // 3125 exactly
    unsigned short* Wp1 = wpk;
    unsigned short* Wp2 = wpk + 3 * DIM * DIM;

    // 3 fused layers, ping-pong hA <-> hB
    k_fused<<<fusedBlocks, 128, 0, stream>>>(hA, offs, deg, ssrc, hB,
                                             Wp1, b1, Wp2, b2, 1);
    k_fused<<<fusedBlocks, 128, 0, stream>>>(hB, offs, deg, ssrc, hA,
                                             Wp1 + DIM * DIM, b1 + DIM,
                                             Wp2 + DIM * DIM, b2 + DIM, 1);
    k_fused<<<fusedBlocks, 128, 0, stream>>>(hA, offs, deg, ssrc, hB,
                                             Wp1 + 2 * DIM * DIM, b1 + 2 * DIM,
                                             Wp2 + 2 * DIM * DIM, b2 + 2 * DIM, 0);

    // two-stage pool
    {
        dim3 g1(NGRAPHS, PCHUNK);
        k_pool1<<<g1, 256, 0, stream>>>(hB, batch, partial);
        k_pool2<<<NGRAPHS, 128, 0, stream>>>(partial, out);
    }
}